// Round 1
// baseline (772.804 us; speedup 1.0000x reference)
//
#include <hip/hip_runtime.h>

#define NXg   128
#define NYg   128
#define NITER 320
#define NSTA  24
#define NPICK 200000
#define INFV  1.0e6f

// ---------------------------------------------------------------------------
// Eikonal solve: one block (1024 threads) per (phase, station).
// Each thread owns a 4x4 tile in registers; LDS holds only the double-buffered
// tile-boundary rows (2 x 32 KiB). Left/right halo via __shfl from the
// neighboring lane's registers.
// ---------------------------------------------------------------------------

template<bool CHK>
__device__ __forceinline__ int eik_step(
    const float (&uo)[4][4], float (&un)[4][4],
    const float (&fh)[4][4], const float (&t2)[4][4],
    const float* hsrc, float* hdst,
    int ti, int tj, int lane)
{
  // vertical halo rows (old values) from LDS
  float tpa[4], bta[4];
  if (ti == 0) {
    tpa[0] = tpa[1] = tpa[2] = tpa[3] = INFV;
  } else {
    float4 tv = *reinterpret_cast<const float4*>(&hsrc[((ti - 1) * 2 + 1) * NYg + tj * 4]);
    tpa[0] = tv.x; tpa[1] = tv.y; tpa[2] = tv.z; tpa[3] = tv.w;
  }
  if (ti == 31) {
    bta[0] = bta[1] = bta[2] = bta[3] = INFV;
  } else {
    float4 bv = *reinterpret_cast<const float4*>(&hsrc[((ti + 1) * 2 + 0) * NYg + tj * 4]);
    bta[0] = bv.x; bta[1] = bv.y; bta[2] = bv.z; bta[3] = bv.w;
  }

  // horizontal halo columns (old values) from neighbor lanes' registers
  float lft[4], rgt[4];
#pragma unroll
  for (int r = 0; r < 4; r++) {
    float xl = __shfl(uo[r][3], lane - 1, 64);
    float xr = __shfl(uo[r][0], lane + 1, 64);
    lft[r] = (tj == 0)  ? INFV : xl;
    rgt[r] = (tj == 31) ? INFV : xr;
  }

  int chg = 0;
#pragma unroll
  for (int r = 0; r < 4; r++) {
#pragma unroll
    for (int c = 0; c < 4; c++) {
      float up = (r == 0) ? tpa[c] : uo[r - 1][c];
      float dn = (r == 3) ? bta[c] : uo[r + 1][c];
      float lf = (c == 0) ? lft[r] : uo[r][c - 1];
      float rt = (c == 3) ? rgt[r] : uo[r][c + 1];
      float a  = fminf(up, dn);            // min x-neighbors
      float b  = fminf(lf, rt);            // min y-neighbors
      float mn = fminf(a, b);
      float dd = a - b;                    // (-dd)*dd == -|d|^2
      float s  = fmaxf(__builtin_fmaf(-dd, dd, t2[r][c]), 0.0f);
      float q  = __builtin_sqrtf(s);
      float tw = 0.5f * ((a + b) + q);     // two-sided
      float on = mn + fh[r][c];            // one-sided
      float cand = (fabsf(dd) >= fh[r][c]) ? on : tw;
      float nv = fminf(uo[r][c], cand);    // monotone min-update
      un[r][c] = nv;
      if (CHK) chg |= (nv != uo[r][c]);
    }
  }

  // publish NEW boundary rows (rows 0 and 3 of the tile) for vertical halos
  *reinterpret_cast<float4*>(&hdst[(ti * 2 + 0) * NYg + tj * 4]) =
      make_float4(un[0][0], un[0][1], un[0][2], un[0][3]);
  *reinterpret_cast<float4*>(&hdst[(ti * 2 + 1) * NYg + tj * 4]) =
      make_float4(un[3][0], un[3][1], un[3][2], un[3][3]);
  return chg;
}

__global__ __launch_bounds__(1024) void eik_kernel(
    const float* __restrict__ vp, const float* __restrict__ vs,
    const float* __restrict__ station_loc, float* __restrict__ tab)
{
  __shared__ float halo[2][32 * 2 * NYg];   // 2 x 32 KiB boundary-row buffers

  const int t    = threadIdx.x;
  const int lane = t & 63;
  const int tj   = t & 31;       // tile col index (grid cols 4*tj .. 4*tj+3)
  const int ti   = t >> 5;       // tile row index (grid rows 4*ti .. 4*ti+3)
  const int b    = blockIdx.x;
  const int st   = b % NSTA;
  const int ph   = b / NSTA;     // 0 = P (vp), 1 = S (vs)
  const float* __restrict__ v = ph ? vs : vp;

  // source cell from station location (H = 1): round-half-even like jnp.round
  const float sx = station_loc[st * 3 + 0];
  const float sy = station_loc[st * 3 + 1];
  int ix = (int)rintf(sx); ix = ix < 0 ? 0 : (ix > NXg - 1 ? NXg - 1 : ix);
  int iy = (int)rintf(sy); iy = iy < 0 ? 0 : (iy > NYg - 1 ? NYg - 1 : iy);

  const int r0 = ti * 4, c0 = tj * 4;
  float fh[4][4], t2[4][4], uA[4][4], uB[4][4];
#pragma unroll
  for (int r = 0; r < 4; r++) {
    float4 vv = *reinterpret_cast<const float4*>(&v[(r0 + r) * NYg + c0]);
    float fr[4] = {1.0f / vv.x, 1.0f / vv.y, 1.0f / vv.z, 1.0f / vv.w};
#pragma unroll
    for (int c = 0; c < 4; c++) {
      float f = fr[c];                 // fh = f*H with H=1
      fh[r][c] = f;
      t2[r][c] = (2.0f * f) * f;       // 2*fh*fh with reference rounding order
      uA[r][c] = ((r0 + r) == ix && (c0 + c) == iy) ? 0.0f : INFV;
    }
  }
  // publish initial boundary rows
  *reinterpret_cast<float4*>(&halo[0][(ti * 2 + 0) * NYg + c0]) =
      make_float4(uA[0][0], uA[0][1], uA[0][2], uA[0][3]);
  *reinterpret_cast<float4*>(&halo[0][(ti * 2 + 1) * NYg + c0]) =
      make_float4(uA[3][0], uA[3][1], uA[3][2], uA[3][3]);
  __syncthreads();

  // 320 iterations = 40 x (8 steps); convergence check every 8th step.
  // The update is monotone + deterministic: zero change => all later
  // iterations are bitwise no-ops, so early exit is exact.
  for (int it = 0; it < NITER; it += 8) {
    eik_step<false>(uA, uB, fh, t2, halo[0], halo[1], ti, tj, lane); __syncthreads();
    eik_step<false>(uB, uA, fh, t2, halo[1], halo[0], ti, tj, lane); __syncthreads();
    eik_step<false>(uA, uB, fh, t2, halo[0], halo[1], ti, tj, lane); __syncthreads();
    eik_step<false>(uB, uA, fh, t2, halo[1], halo[0], ti, tj, lane); __syncthreads();
    eik_step<false>(uA, uB, fh, t2, halo[0], halo[1], ti, tj, lane); __syncthreads();
    eik_step<false>(uB, uA, fh, t2, halo[1], halo[0], ti, tj, lane); __syncthreads();
    eik_step<false>(uA, uB, fh, t2, halo[0], halo[1], ti, tj, lane); __syncthreads();
    int chg = eik_step<true>(uB, uA, fh, t2, halo[1], halo[0], ti, tj, lane);
    if (!__syncthreads_or(chg)) break;
  }

  // result is in uA after an even number of steps
  float* __restrict__ To = tab + (size_t)(ph * NSTA + st) * NXg * NYg;
#pragma unroll
  for (int r = 0; r < 4; r++)
    *reinterpret_cast<float4*>(&To[(r0 + r) * NYg + c0]) =
        make_float4(uA[r][0], uA[r][1], uA[r][2], uA[r][3]);
}

// ---------------------------------------------------------------------------
// Picks: bilinear interp of travel-time table, arrival times, and per-group
// (station,phase) squared-error accumulation (LDS-binned, then global atomics).
// ---------------------------------------------------------------------------
__global__ void picks_kernel(
    const float* __restrict__ evloc, const float* __restrict__ evtime,
    const int* __restrict__ pst, const int* __restrict__ pph,
    const int* __restrict__ pev, const float* __restrict__ ptime,
    const float* __restrict__ tab, float* __restrict__ out,
    float* __restrict__ acc)
{
  __shared__ float lsse[2 * NSTA];
  __shared__ float lcnt[2 * NSTA];
  if (threadIdx.x < 2 * NSTA) { lsse[threadIdx.x] = 0.0f; lcnt[threadIdx.x] = 0.0f; }
  __syncthreads();

  int i = blockIdx.x * blockDim.x + threadIdx.x;
  if (i < NPICK) {
    int e = pev[i], s = pst[i], p = pph[i];
    float x = evloc[e * 3 + 0];
    float y = evloc[e * 3 + 1];
    int ir0 = (int)floorf(x); ir0 = ir0 < 0 ? 0 : (ir0 > NXg - 2 ? NXg - 2 : ir0);
    int iz0 = (int)floorf(y); iz0 = iz0 < 0 ? 0 : (iz0 > NYg - 2 ? NYg - 2 : iz0);
    float xc = fminf(fmaxf(x, 0.0f), (float)(NXg - 1));
    float yc = fminf(fmaxf(y, 0.0f), (float)(NYg - 1));
    float r0f = (float)ir0, z0f = (float)iz0;
    float r1 = r0f + 1.0f, z1 = z0f + 1.0f;

    const float* Tb = tab + (size_t)(p * NSTA + s) * NXg * NYg;
    float Q00 = Tb[ir0 * NYg + iz0];
    float Q01 = Tb[ir0 * NYg + iz0 + 1];
    float Q10 = Tb[(ir0 + 1) * NYg + iz0];
    float Q11 = Tb[(ir0 + 1) * NYg + iz0 + 1];
    // H*H = 1, keep reference's left-assoc ordering
    float tt = Q00 * (r1 - xc) * (z1 - yc) + Q10 * (xc - r0f) * (z1 - yc)
             + Q01 * (r1 - xc) * (yc - z0f) + Q11 * (xc - r0f) * (yc - z0f);
    float at = evtime[e] + tt;
    out[i] = at;

    float dq = at - ptime[i];
    int g = s * 2 + p;
    atomicAdd(&lsse[g], dq * dq);
    atomicAdd(&lcnt[g], 1.0f);
  }
  __syncthreads();
  if (threadIdx.x < 2 * NSTA) {
    atomicAdd(&acc[threadIdx.x], lsse[threadIdx.x]);
    atomicAdd(&acc[2 * NSTA + threadIdx.x], lcnt[threadIdx.x]);
  }
}

__global__ void loss_kernel(const float* __restrict__ acc, float* __restrict__ out)
{
  int l = threadIdx.x;
  float v = 0.0f;
  if (l < 2 * NSTA) v = acc[l] / fmaxf(acc[2 * NSTA + l], 1.0f);
#pragma unroll
  for (int o = 32; o > 0; o >>= 1) v += __shfl_down(v, o, 64);
  if (l == 0) out[NPICK] = v;
}

// ---------------------------------------------------------------------------
extern "C" void kernel_launch(void* const* d_in, const int* in_sizes, int n_in,
                              void* d_out, int out_size, void* d_ws, size_t ws_size,
                              hipStream_t stream)
{
  const float* vp           = (const float*)d_in[0];
  const float* vs           = (const float*)d_in[1];
  const float* station_loc  = (const float*)d_in[2];
  const float* event_loc    = (const float*)d_in[3];
  const float* event_time   = (const float*)d_in[4];
  const int*   pick_station = (const int*)d_in[5];
  const int*   pick_phase   = (const int*)d_in[6];
  const int*   pick_event   = (const int*)d_in[7];
  const float* phase_time   = (const float*)d_in[8];

  float* out = (float*)d_out;
  float* acc = (float*)d_ws;          // [0,48): sse, [48,96): cnt
  float* tab = acc + 256;             // 2*24*128*128 f32 travel-time tables

  hipMemsetAsync(d_ws, 0, 96 * sizeof(float), stream);

  eik_kernel<<<2 * NSTA, 1024, 0, stream>>>(vp, vs, station_loc, tab);

  picks_kernel<<<(NPICK + 255) / 256, 256, 0, stream>>>(
      event_loc, event_time, pick_station, pick_phase, pick_event, phase_time,
      tab, out, acc);

  loss_kernel<<<1, 64, 0, stream>>>(acc, out);
}

// Round 2
// 634.915 us; speedup vs baseline: 1.2172x; 1.2172x over previous
//
#include <hip/hip_runtime.h>

#define NXg   128
#define NYg   128
#define NSTA  24
#define NPICK 200000
#define INFV  1.0e6f
#define TS    8        // cells per thread per dim
#define TG    16       // tile grid is 16x16 tiles (256 threads)
#define MAX_OUTER 96   // 96*4 = 384 GS passes >= 320 Jacobi iters (safety cap)

// ---------------------------------------------------------------------------
// Eikonal: one block (256 threads) per (phase, station).
// Each thread owns an 8x8 cell tile fully in registers. Per outer iteration:
// read 4 halo edges from LDS, run 4 directional in-place Gauss-Seidel sweeps
// (fast-sweeping orders), publish own edges, block-wide convergence check.
// Monotone min-updates => converges to the same fixed point as the
// reference's 320 Jacobi iterations; early exit is exact at convergence.
// ---------------------------------------------------------------------------

template<int DR, int DC>
__device__ __forceinline__ void gs_pass(
    float (&u)[TS][TS], const float (&fh)[TS][TS],
    const float (&tpa)[TS], const float (&bta)[TS],
    const float (&lfa)[TS], const float (&rga)[TS], int &chg)
{
#pragma unroll
  for (int rr = 0; rr < TS; rr++) {
    const int r = (DR > 0) ? rr : (TS - 1 - rr);
#pragma unroll
    for (int cc = 0; cc < TS; cc++) {
      const int c = (DC > 0) ? cc : (TS - 1 - cc);
      const float up = (r == 0)      ? tpa[c] : u[r - 1][c];
      const float dn = (r == TS - 1) ? bta[c] : u[r + 1][c];
      const float lf = (c == 0)      ? lfa[r] : u[r][c - 1];
      const float rt = (c == TS - 1) ? rga[r] : u[r][c + 1];
      const float a  = fminf(up, dn);          // min x-neighbors (rows)
      const float b  = fminf(lf, rt);          // min y-neighbors (cols)
      const float dd = a - b;
      const float w  = fh[r][c];
      const float s  = fmaxf(__builtin_fmaf(-dd, dd, (2.0f * w) * w), 0.0f);
      const float tw = 0.5f * ((a + b) + __builtin_sqrtf(s));
      const float on = fminf(a, b) + w;
      const float cand = (fabsf(dd) >= w) ? on : tw;
      const float old = u[r][c];
      const float nv  = fminf(old, cand);
      chg |= (nv < old);
      u[r][c] = nv;
    }
  }
}

__global__ __launch_bounds__(256, 1) void eik_kernel(
    const float* __restrict__ vp, const float* __restrict__ vs,
    const float* __restrict__ station_loc, float* __restrict__ tab)
{
  // double-buffered tile-edge arrays: [buf][tile][8]
  __shared__ float eT[2][TG * TG][TS];
  __shared__ float eB[2][TG * TG][TS];
  __shared__ float eL[2][TG * TG][TS];
  __shared__ float eR[2][TG * TG][TS];

  const int t  = threadIdx.x;
  const int tj = t & (TG - 1);
  const int ti = t >> 4;
  const int blk = blockIdx.x;
  const int st = blk % NSTA;
  const int ph = blk / NSTA;
  const float* __restrict__ v = ph ? vs : vp;

  // source cell: round-half-even like jnp.round (H = 1)
  const float sx = station_loc[st * 3 + 0];
  const float sy = station_loc[st * 3 + 1];
  int ix = (int)rintf(sx); ix = ix < 0 ? 0 : (ix > NXg - 1 ? NXg - 1 : ix);
  int iy = (int)rintf(sy); iy = iy < 0 ? 0 : (iy > NYg - 1 ? NYg - 1 : iy);

  const int r0 = ti * TS, c0 = tj * TS;
  float u[TS][TS], fh[TS][TS];
#pragma unroll
  for (int r = 0; r < TS; r++) {
    const float4 v0 = *reinterpret_cast<const float4*>(&v[(r0 + r) * NYg + c0]);
    const float4 v1 = *reinterpret_cast<const float4*>(&v[(r0 + r) * NYg + c0 + 4]);
    fh[r][0] = 1.0f / v0.x; fh[r][1] = 1.0f / v0.y;
    fh[r][2] = 1.0f / v0.z; fh[r][3] = 1.0f / v0.w;
    fh[r][4] = 1.0f / v1.x; fh[r][5] = 1.0f / v1.y;
    fh[r][6] = 1.0f / v1.z; fh[r][7] = 1.0f / v1.w;
#pragma unroll
    for (int c = 0; c < TS; c++)
      u[r][c] = ((r0 + r) == ix && (c0 + c) == iy) ? 0.0f : INFV;
  }

  auto publish = [&](int pb) {
    *reinterpret_cast<float4*>(&eT[pb][t][0]) = make_float4(u[0][0], u[0][1], u[0][2], u[0][3]);
    *reinterpret_cast<float4*>(&eT[pb][t][4]) = make_float4(u[0][4], u[0][5], u[0][6], u[0][7]);
    *reinterpret_cast<float4*>(&eB[pb][t][0]) = make_float4(u[7][0], u[7][1], u[7][2], u[7][3]);
    *reinterpret_cast<float4*>(&eB[pb][t][4]) = make_float4(u[7][4], u[7][5], u[7][6], u[7][7]);
    *reinterpret_cast<float4*>(&eL[pb][t][0]) = make_float4(u[0][0], u[1][0], u[2][0], u[3][0]);
    *reinterpret_cast<float4*>(&eL[pb][t][4]) = make_float4(u[4][0], u[5][0], u[6][0], u[7][0]);
    *reinterpret_cast<float4*>(&eR[pb][t][0]) = make_float4(u[0][7], u[1][7], u[2][7], u[3][7]);
    *reinterpret_cast<float4*>(&eR[pb][t][4]) = make_float4(u[4][7], u[5][7], u[6][7], u[7][7]);
  };

  publish(1);
  __syncthreads();

  for (int outer = 0; outer < MAX_OUTER; outer++) {
    const int rb = 1 - (outer & 1);
    const int wb = outer & 1;

    float tpa[TS], bta[TS], lfa[TS], rga[TS];
    {
      float4 h0 = make_float4(INFV, INFV, INFV, INFV), h1 = h0;
      if (ti > 0) {
        h0 = *reinterpret_cast<const float4*>(&eB[rb][t - TG][0]);
        h1 = *reinterpret_cast<const float4*>(&eB[rb][t - TG][4]);
      }
      tpa[0] = h0.x; tpa[1] = h0.y; tpa[2] = h0.z; tpa[3] = h0.w;
      tpa[4] = h1.x; tpa[5] = h1.y; tpa[6] = h1.z; tpa[7] = h1.w;
    }
    {
      float4 h0 = make_float4(INFV, INFV, INFV, INFV), h1 = h0;
      if (ti < TG - 1) {
        h0 = *reinterpret_cast<const float4*>(&eT[rb][t + TG][0]);
        h1 = *reinterpret_cast<const float4*>(&eT[rb][t + TG][4]);
      }
      bta[0] = h0.x; bta[1] = h0.y; bta[2] = h0.z; bta[3] = h0.w;
      bta[4] = h1.x; bta[5] = h1.y; bta[6] = h1.z; bta[7] = h1.w;
    }
    {
      float4 h0 = make_float4(INFV, INFV, INFV, INFV), h1 = h0;
      if (tj > 0) {
        h0 = *reinterpret_cast<const float4*>(&eR[rb][t - 1][0]);
        h1 = *reinterpret_cast<const float4*>(&eR[rb][t - 1][4]);
      }
      lfa[0] = h0.x; lfa[1] = h0.y; lfa[2] = h0.z; lfa[3] = h0.w;
      lfa[4] = h1.x; lfa[5] = h1.y; lfa[6] = h1.z; lfa[7] = h1.w;
    }
    {
      float4 h0 = make_float4(INFV, INFV, INFV, INFV), h1 = h0;
      if (tj < TG - 1) {
        h0 = *reinterpret_cast<const float4*>(&eL[rb][t + 1][0]);
        h1 = *reinterpret_cast<const float4*>(&eL[rb][t + 1][4]);
      }
      rga[0] = h0.x; rga[1] = h0.y; rga[2] = h0.z; rga[3] = h0.w;
      rga[4] = h1.x; rga[5] = h1.y; rga[6] = h1.z; rga[7] = h1.w;
    }

    int chg = 0;
    gs_pass<+1, +1>(u, fh, tpa, bta, lfa, rga, chg);
    gs_pass<+1, -1>(u, fh, tpa, bta, lfa, rga, chg);
    gs_pass<-1, +1>(u, fh, tpa, bta, lfa, rga, chg);
    gs_pass<-1, -1>(u, fh, tpa, bta, lfa, rga, chg);

    publish(wb);
    if (!__syncthreads_or(chg)) break;
  }

  float* __restrict__ To = tab + (size_t)(ph * NSTA + st) * NXg * NYg;
#pragma unroll
  for (int r = 0; r < TS; r++) {
    *reinterpret_cast<float4*>(&To[(r0 + r) * NYg + c0]) =
        make_float4(u[r][0], u[r][1], u[r][2], u[r][3]);
    *reinterpret_cast<float4*>(&To[(r0 + r) * NYg + c0 + 4]) =
        make_float4(u[r][4], u[r][5], u[r][6], u[r][7]);
  }
}

// ---------------------------------------------------------------------------
// Picks: bilinear interp + arrival times + per-(station,phase) MSE pieces.
// ---------------------------------------------------------------------------
__global__ void picks_kernel(
    const float* __restrict__ evloc, const float* __restrict__ evtime,
    const int* __restrict__ pst, const int* __restrict__ pph,
    const int* __restrict__ pev, const float* __restrict__ ptime,
    const float* __restrict__ tab, float* __restrict__ out,
    float* __restrict__ acc)
{
  __shared__ float lsse[2 * NSTA];
  __shared__ float lcnt[2 * NSTA];
  if (threadIdx.x < 2 * NSTA) { lsse[threadIdx.x] = 0.0f; lcnt[threadIdx.x] = 0.0f; }
  __syncthreads();

  int i = blockIdx.x * blockDim.x + threadIdx.x;
  if (i < NPICK) {
    int e = pev[i], s = pst[i], p = pph[i];
    float x = evloc[e * 3 + 0];
    float y = evloc[e * 3 + 1];
    int ir0 = (int)floorf(x); ir0 = ir0 < 0 ? 0 : (ir0 > NXg - 2 ? NXg - 2 : ir0);
    int iz0 = (int)floorf(y); iz0 = iz0 < 0 ? 0 : (iz0 > NYg - 2 ? NYg - 2 : iz0);
    float xc = fminf(fmaxf(x, 0.0f), (float)(NXg - 1));
    float yc = fminf(fmaxf(y, 0.0f), (float)(NYg - 1));
    float r0f = (float)ir0, z0f = (float)iz0;
    float r1 = r0f + 1.0f, z1 = z0f + 1.0f;

    const float* Tb = tab + (size_t)(p * NSTA + s) * NXg * NYg;
    float Q00 = Tb[ir0 * NYg + iz0];
    float Q01 = Tb[ir0 * NYg + iz0 + 1];
    float Q10 = Tb[(ir0 + 1) * NYg + iz0];
    float Q11 = Tb[(ir0 + 1) * NYg + iz0 + 1];
    float tt = Q00 * (r1 - xc) * (z1 - yc) + Q10 * (xc - r0f) * (z1 - yc)
             + Q01 * (r1 - xc) * (yc - z0f) + Q11 * (xc - r0f) * (yc - z0f);
    float at = evtime[e] + tt;
    out[i] = at;

    float dq = at - ptime[i];
    int g = s * 2 + p;
    atomicAdd(&lsse[g], dq * dq);
    atomicAdd(&lcnt[g], 1.0f);
  }
  __syncthreads();
  if (threadIdx.x < 2 * NSTA) {
    atomicAdd(&acc[threadIdx.x], lsse[threadIdx.x]);
    atomicAdd(&acc[2 * NSTA + threadIdx.x], lcnt[threadIdx.x]);
  }
}

__global__ void loss_kernel(const float* __restrict__ acc, float* __restrict__ out)
{
  int l = threadIdx.x;
  float v = 0.0f;
  if (l < 2 * NSTA) v = acc[l] / fmaxf(acc[2 * NSTA + l], 1.0f);
#pragma unroll
  for (int o = 32; o > 0; o >>= 1) v += __shfl_down(v, o, 64);
  if (l == 0) out[NPICK] = v;
}

// ---------------------------------------------------------------------------
extern "C" void kernel_launch(void* const* d_in, const int* in_sizes, int n_in,
                              void* d_out, int out_size, void* d_ws, size_t ws_size,
                              hipStream_t stream)
{
  const float* vp           = (const float*)d_in[0];
  const float* vs           = (const float*)d_in[1];
  const float* station_loc  = (const float*)d_in[2];
  const float* event_loc    = (const float*)d_in[3];
  const float* event_time   = (const float*)d_in[4];
  const int*   pick_station = (const int*)d_in[5];
  const int*   pick_phase   = (const int*)d_in[6];
  const int*   pick_event   = (const int*)d_in[7];
  const float* phase_time   = (const float*)d_in[8];

  float* out = (float*)d_out;
  float* acc = (float*)d_ws;          // [0,48): sse, [48,96): cnt
  float* tab = acc + 256;             // 2*24*128*128 f32 travel-time tables

  hipMemsetAsync(d_ws, 0, 96 * sizeof(float), stream);

  eik_kernel<<<2 * NSTA, 256, 0, stream>>>(vp, vs, station_loc, tab);

  picks_kernel<<<(NPICK + 255) / 256, 256, 0, stream>>>(
      event_loc, event_time, pick_station, pick_phase, pick_event, phase_time,
      tab, out, acc);

  loss_kernel<<<1, 64, 0, stream>>>(acc, out);
}

// Round 4
// 320.695 us; speedup vs baseline: 2.4098x; 1.9798x over previous
//
#include <hip/hip_runtime.h>

#define NXg   128
#define NYg   128
#define NSTA  24
#define NPICK 200000
#define INFV  1.0e6f
#define TS    8        // cells per thread per dim
#define TG    16       // tile grid is 16x16 tiles (256 threads)
#define MAXO  200      // safety cap; early exit is exact

// raw v_sqrt_f32 (~1 ulp) — skips the IEEE fixup chain
__device__ __forceinline__ float fsqrt_fast(float x) {
#if __has_builtin(__builtin_amdgcn_sqrtf)
  return __builtin_amdgcn_sqrtf(x);
#else
  float r; asm("v_sqrt_f32 %0, %1" : "=v"(r) : "v"(x)); return r;
#endif
}

// ---------------------------------------------------------------------------
// Eikonal: one block (256 threads) per (phase, station).
// Thread = 8x8 cell tile in registers; wave = 8x8 tile quadrant (64x64 cells).
// Single-buffered LDS edges (always hold each tile's CURRENT values) with a
// two-barrier outer loop:
//   [read flags + halos, compute]  -> barrier ->  [write flag, publish]  -> barrier(or)
// Read and write regions are disjoint => no race, no staleness.
// Wave-level skip is exact: fixed per-outer operator (4 GS passes) + monotone
// min-update + unchanged inputs => bitwise no-op.
// ---------------------------------------------------------------------------

template<int DR, int DC>
__device__ __forceinline__ void gs_pass(
    float (&u)[TS][TS], const float (&fh)[TS][TS], const float (&t2)[TS][TS],
    const float (&tpa)[TS], const float (&bta)[TS],
    const float (&lfa)[TS], const float (&rga)[TS], int &chg)
{
#pragma unroll
  for (int rr = 0; rr < TS; rr++) {
    const int r = (DR > 0) ? rr : (TS - 1 - rr);
#pragma unroll
    for (int cc = 0; cc < TS; cc++) {
      const int c = (DC > 0) ? cc : (TS - 1 - cc);
      const float up = (r == 0)      ? tpa[c] : u[r - 1][c];
      const float dn = (r == TS - 1) ? bta[c] : u[r + 1][c];
      const float lf = (c == 0)      ? lfa[r] : u[r][c - 1];
      const float rt = (c == TS - 1) ? rga[r] : u[r][c + 1];
      const float a  = fminf(up, dn);          // min x-neighbors (rows)
      const float b  = fminf(lf, rt);          // min y-neighbors (cols)
      const float dd = a - b;
      const float w  = fh[r][c];
      const float s  = fmaxf(__builtin_fmaf(-dd, dd, t2[r][c]), 0.0f);
      const float tw = 0.5f * ((a + b) + fsqrt_fast(s));
      const float on = fminf(a, b) + w;
      const float cand = (fabsf(dd) >= w) ? on : tw;
      const float old = u[r][c];
      chg |= (cand < old);
      u[r][c] = fminf(old, cand);
    }
  }
}

__global__ __launch_bounds__(256, 1) void eik_kernel(
    const float* __restrict__ vp, const float* __restrict__ vs,
    const float* __restrict__ station_loc, float* __restrict__ tab)
{
  // single-buffered tile-edge arrays: [tile][8]  (32 KiB total)
  __shared__ float eT[TG * TG][TS];
  __shared__ float eB[TG * TG][TS];
  __shared__ float eL[TG * TG][TS];
  __shared__ float eR[TG * TG][TS];
  // per-tile change flags with zero border ring (single array; read/write
  // regions are separated by the mid-barrier)
  __shared__ int flg[TG + 2][TG + 2];

  const int t    = threadIdx.x;
  const int wv   = t >> 6;
  const int lane = t & 63;
  // wave <-> 8x8-tile quadrant mapping (skip granularity = wave)
  const int ti = (wv >> 1) * 8 + (lane >> 3);
  const int tj = (wv & 1) * 8 + (lane & 7);
  const int tid = ti * TG + tj;
  const int fi = ti + 1, fj = tj + 1;

  const int blk = blockIdx.x;
  const int st = blk % NSTA;
  const int ph = blk / NSTA;
  const float* __restrict__ v = ph ? vs : vp;

  // flags init: interior = 1 (everyone active at outer 0), border ring = 0
  for (int i = t; i < (TG + 2) * (TG + 2); i += 256) {
    const int r = i / (TG + 2), c = i % (TG + 2);
    (&flg[0][0])[i] = (r >= 1 && r <= TG && c >= 1 && c <= TG) ? 1 : 0;
  }

  // source cell: round-half-even like jnp.round (H = 1)
  const float sx = station_loc[st * 3 + 0];
  const float sy = station_loc[st * 3 + 1];
  int ix = (int)rintf(sx); ix = ix < 0 ? 0 : (ix > NXg - 1 ? NXg - 1 : ix);
  int iy = (int)rintf(sy); iy = iy < 0 ? 0 : (iy > NYg - 1 ? NYg - 1 : iy);

  const int r0 = ti * TS, c0 = tj * TS;
  float u[TS][TS], fh[TS][TS], t2[TS][TS];
#pragma unroll
  for (int r = 0; r < TS; r++) {
    const float4 v0 = *reinterpret_cast<const float4*>(&v[(r0 + r) * NYg + c0]);
    const float4 v1 = *reinterpret_cast<const float4*>(&v[(r0 + r) * NYg + c0 + 4]);
    fh[r][0] = 1.0f / v0.x; fh[r][1] = 1.0f / v0.y;
    fh[r][2] = 1.0f / v0.z; fh[r][3] = 1.0f / v0.w;
    fh[r][4] = 1.0f / v1.x; fh[r][5] = 1.0f / v1.y;
    fh[r][6] = 1.0f / v1.z; fh[r][7] = 1.0f / v1.w;
#pragma unroll
    for (int c = 0; c < TS; c++) {
      t2[r][c] = (2.0f * fh[r][c]) * fh[r][c];
      u[r][c] = ((r0 + r) == ix && (c0 + c) == iy) ? 0.0f : INFV;
    }
  }

  auto publish = [&]() {
    *reinterpret_cast<float4*>(&eT[tid][0]) = make_float4(u[0][0], u[0][1], u[0][2], u[0][3]);
    *reinterpret_cast<float4*>(&eT[tid][4]) = make_float4(u[0][4], u[0][5], u[0][6], u[0][7]);
    *reinterpret_cast<float4*>(&eB[tid][0]) = make_float4(u[7][0], u[7][1], u[7][2], u[7][3]);
    *reinterpret_cast<float4*>(&eB[tid][4]) = make_float4(u[7][4], u[7][5], u[7][6], u[7][7]);
    *reinterpret_cast<float4*>(&eL[tid][0]) = make_float4(u[0][0], u[1][0], u[2][0], u[3][0]);
    *reinterpret_cast<float4*>(&eL[tid][4]) = make_float4(u[4][0], u[5][0], u[6][0], u[7][0]);
    *reinterpret_cast<float4*>(&eR[tid][0]) = make_float4(u[0][7], u[1][7], u[2][7], u[3][7]);
    *reinterpret_cast<float4*>(&eR[tid][4]) = make_float4(u[4][7], u[5][7], u[6][7], u[7][7]);
  };

  publish();
  __syncthreads();

  for (int outer = 0; outer < MAXO; outer++) {
    // ---- read region: flags + halos (current values), compute ----
    const int nb = flg[fi][fj]
                 | flg[fi - 1][fj] | flg[fi + 1][fj]
                 | flg[fi][fj - 1] | flg[fi][fj + 1];
    int chg = 0;
    if (__any(nb)) {
      float tpa[TS], bta[TS], lfa[TS], rga[TS];
      {
        float4 h0 = make_float4(INFV, INFV, INFV, INFV), h1 = h0;
        if (ti > 0) {
          h0 = *reinterpret_cast<const float4*>(&eB[tid - TG][0]);
          h1 = *reinterpret_cast<const float4*>(&eB[tid - TG][4]);
        }
        tpa[0] = h0.x; tpa[1] = h0.y; tpa[2] = h0.z; tpa[3] = h0.w;
        tpa[4] = h1.x; tpa[5] = h1.y; tpa[6] = h1.z; tpa[7] = h1.w;
      }
      {
        float4 h0 = make_float4(INFV, INFV, INFV, INFV), h1 = h0;
        if (ti < TG - 1) {
          h0 = *reinterpret_cast<const float4*>(&eT[tid + TG][0]);
          h1 = *reinterpret_cast<const float4*>(&eT[tid + TG][4]);
        }
        bta[0] = h0.x; bta[1] = h0.y; bta[2] = h0.z; bta[3] = h0.w;
        bta[4] = h1.x; bta[5] = h1.y; bta[6] = h1.z; bta[7] = h1.w;
      }
      {
        float4 h0 = make_float4(INFV, INFV, INFV, INFV), h1 = h0;
        if (tj > 0) {
          h0 = *reinterpret_cast<const float4*>(&eR[tid - 1][0]);
          h1 = *reinterpret_cast<const float4*>(&eR[tid - 1][4]);
        }
        lfa[0] = h0.x; lfa[1] = h0.y; lfa[2] = h0.z; lfa[3] = h0.w;
        lfa[4] = h1.x; lfa[5] = h1.y; lfa[6] = h1.z; lfa[7] = h1.w;
      }
      {
        float4 h0 = make_float4(INFV, INFV, INFV, INFV), h1 = h0;
        if (tj < TG - 1) {
          h0 = *reinterpret_cast<const float4*>(&eL[tid + 1][0]);
          h1 = *reinterpret_cast<const float4*>(&eL[tid + 1][4]);
        }
        rga[0] = h0.x; rga[1] = h0.y; rga[2] = h0.z; rga[3] = h0.w;
        rga[4] = h1.x; rga[5] = h1.y; rga[6] = h1.z; rga[7] = h1.w;
      }

      gs_pass<+1, +1>(u, fh, t2, tpa, bta, lfa, rga, chg);
      gs_pass<+1, -1>(u, fh, t2, tpa, bta, lfa, rga, chg);
      gs_pass<-1, +1>(u, fh, t2, tpa, bta, lfa, rga, chg);
      gs_pass<-1, -1>(u, fh, t2, tpa, bta, lfa, rga, chg);
    }

    __syncthreads();   // all reads of edges/flags done before any write

    // ---- write region: flag + edges (only if changed) ----
    flg[fi][fj] = chg;
    if (chg) publish();

    if (!__syncthreads_or(chg)) break;
  }

  float* __restrict__ To = tab + (size_t)(ph * NSTA + st) * NXg * NYg;
#pragma unroll
  for (int r = 0; r < TS; r++) {
    *reinterpret_cast<float4*>(&To[(r0 + r) * NYg + c0]) =
        make_float4(u[r][0], u[r][1], u[r][2], u[r][3]);
    *reinterpret_cast<float4*>(&To[(r0 + r) * NYg + c0 + 4]) =
        make_float4(u[r][4], u[r][5], u[r][6], u[r][7]);
  }
}

// ---------------------------------------------------------------------------
// Picks: bilinear interp + arrival times + per-(station,phase) MSE pieces.
// ---------------------------------------------------------------------------
__global__ void picks_kernel(
    const float* __restrict__ evloc, const float* __restrict__ evtime,
    const int* __restrict__ pst, const int* __restrict__ pph,
    const int* __restrict__ pev, const float* __restrict__ ptime,
    const float* __restrict__ tab, float* __restrict__ out,
    float* __restrict__ acc)
{
  __shared__ float lsse[2 * NSTA];
  __shared__ float lcnt[2 * NSTA];
  if (threadIdx.x < 2 * NSTA) { lsse[threadIdx.x] = 0.0f; lcnt[threadIdx.x] = 0.0f; }
  __syncthreads();

  int i = blockIdx.x * blockDim.x + threadIdx.x;
  if (i < NPICK) {
    int e = pev[i], s = pst[i], p = pph[i];
    float x = evloc[e * 3 + 0];
    float y = evloc[e * 3 + 1];
    int ir0 = (int)floorf(x); ir0 = ir0 < 0 ? 0 : (ir0 > NXg - 2 ? NXg - 2 : ir0);
    int iz0 = (int)floorf(y); iz0 = iz0 < 0 ? 0 : (iz0 > NYg - 2 ? NYg - 2 : iz0);
    float xc = fminf(fmaxf(x, 0.0f), (float)(NXg - 1));
    float yc = fminf(fmaxf(y, 0.0f), (float)(NYg - 1));
    float r0f = (float)ir0, z0f = (float)iz0;
    float r1 = r0f + 1.0f, z1 = z0f + 1.0f;

    const float* Tb = tab + (size_t)(p * NSTA + s) * NXg * NYg;
    float Q00 = Tb[ir0 * NYg + iz0];
    float Q01 = Tb[ir0 * NYg + iz0 + 1];
    float Q10 = Tb[(ir0 + 1) * NYg + iz0];
    float Q11 = Tb[(ir0 + 1) * NYg + iz0 + 1];
    float tt = Q00 * (r1 - xc) * (z1 - yc) + Q10 * (xc - r0f) * (z1 - yc)
             + Q01 * (r1 - xc) * (yc - z0f) + Q11 * (xc - r0f) * (yc - z0f);
    float at = evtime[e] + tt;
    out[i] = at;

    float dq = at - ptime[i];
    int g = s * 2 + p;
    atomicAdd(&lsse[g], dq * dq);
    atomicAdd(&lcnt[g], 1.0f);
  }
  __syncthreads();
  if (threadIdx.x < 2 * NSTA) {
    atomicAdd(&acc[threadIdx.x], lsse[threadIdx.x]);
    atomicAdd(&acc[2 * NSTA + threadIdx.x], lcnt[threadIdx.x]);
  }
}

__global__ void loss_kernel(const float* __restrict__ acc, float* __restrict__ out)
{
  int l = threadIdx.x;
  float v = 0.0f;
  if (l < 2 * NSTA) v = acc[l] / fmaxf(acc[2 * NSTA + l], 1.0f);
#pragma unroll
  for (int o = 32; o > 0; o >>= 1) v += __shfl_down(v, o, 64);
  if (l == 0) out[NPICK] = v;
}

// ---------------------------------------------------------------------------
extern "C" void kernel_launch(void* const* d_in, const int* in_sizes, int n_in,
                              void* d_out, int out_size, void* d_ws, size_t ws_size,
                              hipStream_t stream)
{
  const float* vp           = (const float*)d_in[0];
  const float* vs           = (const float*)d_in[1];
  const float* station_loc  = (const float*)d_in[2];
  const float* event_loc    = (const float*)d_in[3];
  const float* event_time   = (const float*)d_in[4];
  const int*   pick_station = (const int*)d_in[5];
  const int*   pick_phase   = (const int*)d_in[6];
  const int*   pick_event   = (const int*)d_in[7];
  const float* phase_time   = (const float*)d_in[8];

  float* out = (float*)d_out;
  float* acc = (float*)d_ws;          // [0,48): sse, [48,96): cnt
  float* tab = acc + 256;             // 2*24*128*128 f32 travel-time tables

  hipMemsetAsync(d_ws, 0, 96 * sizeof(float), stream);

  eik_kernel<<<2 * NSTA, 256, 0, stream>>>(vp, vs, station_loc, tab);

  picks_kernel<<<(NPICK + 255) / 256, 256, 0, stream>>>(
      event_loc, event_time, pick_station, pick_phase, pick_event, phase_time,
      tab, out, acc);

  loss_kernel<<<1, 64, 0, stream>>>(acc, out);
}